// Round 4
// baseline (792.340 us; speedup 1.0000x reference)
//
#include <hip/hip_runtime.h>

#define BATCH 4
#define NS    512
#define XS    1024

typedef float  f32x4  __attribute__((ext_vector_type(4)));
typedef float  f32x16 __attribute__((ext_vector_type(16)));
typedef __bf16 bf16x8 __attribute__((ext_vector_type(8)));
typedef unsigned int uintx4 __attribute__((ext_vector_type(4)));

// LDS layout (bytes)
#define WF_OFF   0        // 6*8*64*16 = 49152 : W^T as 32x32x16 A-frags (bf16)
#define BC_OFF   49152    // 6*2*2*16*4 = 1536 : 2*log2e * b_h, [d][nf][hi][q]
#define WIN_OFF  50688    // 64*4 : W_in  [nf][hi][q]
#define BIN_OFF  50944    // 64*4 : b_in
#define WOUT_OFF 51200    // 64*4 : W_out
#define R_OFF    51456    // 512*4
#define PART_OFF 53504    // 8*3*4
#define SMEM_BYTES 53600  // x2 = 107200 <= 160K -> 2 blocks/CU

#define C2 2.8853900817779268f   // 2*log2(e)

__device__ __forceinline__ unsigned int f2bf(float f) {   // fp32->bf16 RNE
    unsigned int u = __float_as_uint(f);
    u += 0x7fffu + ((u >> 16) & 1u);
    return u >> 16;
}
__device__ __forceinline__ unsigned int cvtpk(float lo, float hi) {
    unsigned int r;
    asm("v_cvt_pk_bf16_f32 %0, %1, %2" : "=v"(r) : "v"(lo), "v"(hi));
    return r;
}

extern "C" __global__ __launch_bounds__(512, 4)
void neurop_kernel(const float* __restrict__ yu, const float* __restrict__ x,
                   const float* __restrict__ W_in, const float* __restrict__ b_in,
                   const float* __restrict__ W_h, const float* __restrict__ b_h,
                   const float* __restrict__ W_out, const float* __restrict__ b_out,
                   float* __restrict__ out)
{
    extern __shared__ char smem[];
    unsigned short* wf  = (unsigned short*)(smem + WF_OFF);
    float* bc_s   = (float*)(smem + BC_OFF);
    float* win_s  = (float*)(smem + WIN_OFF);
    float* bin_s  = (float*)(smem + BIN_OFF);
    float* wout_s = (float*)(smem + WOUT_OFF);
    float* r_s    = (float*)(smem + R_OFF);
    float* part   = (float*)(smem + PART_OFF);

    const int t  = threadIdx.x;
    const int l  = t & 63;
    const int wv = t >> 6;
    const int hi = l >> 5;        // 32-lane half
    const int c  = l & 31;        // col within 32-frag
    const int blk = blockIdx.x;   // b*XS + xi
    const int b   = blk >> 10;

    // ---- stage W^T as A-frags: elem f=((d*8+npf*4+kt)*64+lane)*8+j ----
    #pragma unroll 1
    for (int it = 0; it < 48; ++it) {
        int f    = t + it * 512;
        int j    = f & 7;
        int lane = (f >> 3) & 63;
        int fi   = (f >> 9) & 7;
        int d    = f >> 12;
        int kt   = fi & 3;
        int npf  = fi >> 2;
        int row  = 16 * kt + 8 * (lane >> 5) + j;   // k index = n (contraction)
        int col  = 32 * npf + (lane & 31);          // row of W^T = n'
        wf[f] = (unsigned short)f2bf(W_h[(d << 12) + (row << 6) + col]);
    }
    if (t < 384) {   // bias, pre-scaled into exp2 domain
        int q = t & 15, h2 = (t >> 4) & 1, nf = (t >> 5) & 1, d = t >> 6;
        int n = 32 * nf + 4 * h2 + (q & 3) + 8 * (q >> 2);
        bc_s[t] = C2 * b_h[d * 64 + n];
    }
    if (t < 64) {    // W_in/b_in/W_out in C-frag-row order [nf][hi][q]
        int q = t & 15, h2 = (t >> 4) & 1, nf = (t >> 5) & 1;
        int n = 32 * nf + 4 * h2 + (q & 3) + 8 * (q >> 2);
        win_s[t] = W_in[n]; bin_s[t] = b_in[n]; wout_s[t] = W_out[n];
    }
    // ---- r for this wave's 64 sensors ----
    const float x0 = x[blk * 2 + 0], x1 = x[blk * 2 + 1];
    {
        const float* yr = yu + (b * NS + wv * 64 + l) * 5;
        float d0 = x0 - yr[3], d1 = x1 - yr[4];
        r_s[wv * 64 + l] = d0 * d0 + d1 * d1;
    }
    __syncthreads();

    const float rm0 = r_s[wv * 64 + c];        // sensor col for mf=0
    const float rm1 = r_s[wv * 64 + 32 + c];   // mf=1

    // ---- input layer: T[n][m] = r_m*W_in[n]+b_in[n], C-frag layout ----
    float T[2][2][16];
    #pragma unroll
    for (int nf = 0; nf < 2; ++nf)
        #pragma unroll
        for (int qc = 0; qc < 4; ++qc) {
            f32x4 w4 = *(const f32x4*)(win_s + (nf * 2 + hi) * 16 + qc * 4);
            f32x4 b4 = *(const f32x4*)(bin_s + (nf * 2 + hi) * 16 + qc * 4);
            #pragma unroll
            for (int r = 0; r < 4; ++r) {
                T[nf][0][qc * 4 + r] = fmaf(rm0, w4[r], b4[r]);
                T[nf][1][qc * 4 + r] = fmaf(rm1, w4[r], b4[r]);
            }
        }

    const char*  awf = smem + WF_OFF + l * 16;                   // + d*8192 + frag*1024
    const float* abc = (const float*)(smem + BC_OFF) + hi * 16;  // + d*64 + npf*32 + qc*4

    // ---- 6 residual layers, no barriers ----
    #pragma unroll 1
    for (int d = 0; d < 6; ++d) {
        const char*  awd = awf + d * 8192;
        const float* abd = abc + d * 64;
        #pragma unroll
        for (int mf = 0; mf < 2; ++mf) {
            // pack T[*][mf] (C-layout f32) -> B-frags (bf16, k=hi*8+j)
            unsigned int B[4][4];
            #pragma unroll
            for (int nfs = 0; nfs < 2; ++nfs) {
                unsigned int P[4][2];
                #pragma unroll
                for (int qq = 0; qq < 4; ++qq) {
                    P[qq][0] = cvtpk(T[nfs][mf][4 * qq + 0], T[nfs][mf][4 * qq + 1]);
                    P[qq][1] = cvtpk(T[nfs][mf][4 * qq + 2], T[nfs][mf][4 * qq + 3]);
                }
                // v_permlane32_swap_b32 vdst, vsrc : vdst.hi <-> vsrc.lo
                //   new vdst = [dst.lo | src.lo]  -> B reg pi   (features 8qq..)
                //   new vsrc = [dst.hi | src.hi]  -> B reg 2+pi (features 8qq+4..)
                #pragma unroll
                for (int pi = 0; pi < 2; ++pi) {
                    asm("v_permlane32_swap_b32 %0, %1" : "+v"(P[0][pi]), "+v"(P[1][pi]));
                    B[2 * nfs][pi]     = P[0][pi];
                    B[2 * nfs][2 + pi] = P[1][pi];
                    asm("v_permlane32_swap_b32 %0, %1" : "+v"(P[2][pi]), "+v"(P[3][pi]));
                    B[2 * nfs + 1][pi]     = P[2][pi];
                    B[2 * nfs + 1][2 + pi] = P[3][pi];
                }
            }
            #pragma unroll
            for (int npf = 0; npf < 2; ++npf) {
                f32x16 z;
                #pragma unroll
                for (int q = 0; q < 16; ++q) z[q] = 0.0f;
                #pragma unroll
                for (int kt = 0; kt < 4; ++kt) {
                    bf16x8 a = *(const bf16x8*)(awd + (npf * 4 + kt) * 1024);
                    uintx4 ub;
                    ub[0] = B[kt][0]; ub[1] = B[kt][1]; ub[2] = B[kt][2]; ub[3] = B[kt][3];
                    bf16x8 vb = __builtin_bit_cast(bf16x8, ub);
                    z = __builtin_amdgcn_mfma_f32_32x32x16_bf16(a, vb, z, 0, 0, 0);
                }
                // epilogue: T += tanh(z+b) = T + 1 - 2/(exp2(C2*z + C2*b)+1)
                #pragma unroll
                for (int qc = 0; qc < 4; ++qc) {
                    f32x4 bb = *(const f32x4*)(abd + npf * 32 + qc * 4);
                    #pragma unroll
                    for (int r = 0; r < 4; ++r) {
                        int q = qc * 4 + r;
                        float arg = fmaf(z[q], C2, bb[r]);
                        float e   = exp2f(arg);
                        float rc  = __fdividef(2.0f, e + 1.0f);
                        T[npf][mf][q] = (T[npf][mf][q] + 1.0f) - rc;
                    }
                }
            }
        }
    }

    // ---- k = T . W_out (+b_out), then integral over sensors ----
    float ps0 = 0.0f, ps1 = 0.0f;
    #pragma unroll
    for (int nf = 0; nf < 2; ++nf)
        #pragma unroll
        for (int qc = 0; qc < 4; ++qc) {
            f32x4 w4 = *(const f32x4*)(wout_s + (nf * 2 + hi) * 16 + qc * 4);
            #pragma unroll
            for (int r = 0; r < 4; ++r) {
                ps0 = fmaf(T[nf][0][qc * 4 + r], w4[r], ps0);
                ps1 = fmaf(T[nf][1][qc * 4 + r], w4[r], ps1);
            }
        }
    ps0 += __shfl_xor(ps0, 32);
    ps1 += __shfl_xor(ps1, 32);
    const float kv = (hi ? ps1 : ps0) + b_out[0];
    const int sl = wv * 64 + hi * 32 + c;
    const float* ur = yu + (b * NS + sl) * 5;
    float v0 = kv * ur[0], v1 = kv * ur[1], v2 = kv * ur[2];
    #pragma unroll
    for (int off = 1; off < 64; off <<= 1) {
        v0 += __shfl_xor(v0, off);
        v1 += __shfl_xor(v1, off);
        v2 += __shfl_xor(v2, off);
    }
    if (l == 0) { part[wv * 3 + 0] = v0; part[wv * 3 + 1] = v1; part[wv * 3 + 2] = v2; }
    __syncthreads();
    if (t < 3) {
        float s = 0.0f;
        #pragma unroll
        for (int w = 0; w < 8; ++w) s += part[w * 3 + t];
        out[blk * 3 + t] = s * (1.0f / 512.0f);
    }
}

extern "C" void kernel_launch(void* const* d_in, const int* in_sizes, int n_in,
                              void* d_out, int out_size, void* d_ws, size_t ws_size,
                              hipStream_t stream) {
    const float* yu    = (const float*)d_in[0];
    const float* x     = (const float*)d_in[1];
    const float* W_in  = (const float*)d_in[2];
    const float* b_in  = (const float*)d_in[3];
    const float* W_h   = (const float*)d_in[4];
    const float* b_h   = (const float*)d_in[5];
    const float* W_out = (const float*)d_in[6];
    const float* b_out = (const float*)d_in[7];
    float* out = (float*)d_out;

    (void)hipFuncSetAttribute((const void*)neurop_kernel,
                              hipFuncAttributeMaxDynamicSharedMemorySize, SMEM_BYTES);
    hipLaunchKernelGGL(neurop_kernel, dim3(BATCH * XS), dim3(NS), SMEM_BYTES, stream,
                       yu, x, W_in, b_in, W_h, b_h, W_out, b_out, out);
}

// Round 5
// 413.438 us; speedup vs baseline: 1.9165x; 1.9165x over previous
//
#include <hip/hip_runtime.h>

#define BATCH 4
#define NS    512
#define XS    1024

typedef float  f32x4  __attribute__((ext_vector_type(4)));
typedef float  f32x16 __attribute__((ext_vector_type(16)));
typedef __bf16 bf16x8 __attribute__((ext_vector_type(8)));
typedef unsigned int uintx4 __attribute__((ext_vector_type(4)));

// LDS layout (bytes)
#define WF_OFF   0        // 6*8*64*16 = 49152 : W^T as 32x32x16 A-frags (bf16)
#define BC_OFF   49152    // 6*2*2*16*4 = 1536 : 2*log2e * b_h, [d][nf][hi][q]
#define WIN_OFF  50688    // 64*4 : W_in  [nf][hi][q]
#define BIN_OFF  50944    // 64*4 : b_in
#define WOUT_OFF 51200    // 64*4 : W_out
#define R_OFF    51456    // 512*4
#define PART_OFF 53504    // 8*3*4
#define SMEM_BYTES 53600

#define C2 2.8853900817779268f   // 2*log2(e)

__device__ __forceinline__ unsigned int f2bf(float f) {   // fp32->bf16 RNE
    unsigned int u = __float_as_uint(f);
    u += 0x7fffu + ((u >> 16) & 1u);
    return u >> 16;
}
__device__ __forceinline__ unsigned int cvtpk(float lo, float hi) {
    unsigned int r;
    asm("v_cvt_pk_bf16_f32 %0, %1, %2" : "=v"(r) : "v"(lo), "v"(hi));
    return r;
}

extern "C" __global__ __launch_bounds__(512, 2)
void neurop_kernel(const float* __restrict__ yu, const float* __restrict__ x,
                   const float* __restrict__ W_in, const float* __restrict__ b_in,
                   const float* __restrict__ W_h, const float* __restrict__ b_h,
                   const float* __restrict__ W_out, const float* __restrict__ b_out,
                   float* __restrict__ out)
{
    extern __shared__ char smem[];
    unsigned short* wf  = (unsigned short*)(smem + WF_OFF);
    float* bc_s   = (float*)(smem + BC_OFF);
    float* win_s  = (float*)(smem + WIN_OFF);
    float* bin_s  = (float*)(smem + BIN_OFF);
    float* wout_s = (float*)(smem + WOUT_OFF);
    float* r_s    = (float*)(smem + R_OFF);
    float* part   = (float*)(smem + PART_OFF);

    const int t  = threadIdx.x;
    const int l  = t & 63;
    const int wv = t >> 6;
    const int hi = l >> 5;        // 32-lane half
    const int c  = l & 31;        // col within 32-frag
    const int blk = blockIdx.x;   // b*XS + xi
    const int b   = blk >> 10;

    // ---- stage W^T as A-frags: elem f=((d*8+npf*4+kt)*64+lane)*8+j ----
    #pragma unroll 1
    for (int it = 0; it < 48; ++it) {
        int f    = t + it * 512;
        int j    = f & 7;
        int lane = (f >> 3) & 63;
        int fi   = (f >> 9) & 7;
        int d    = f >> 12;
        int kt   = fi & 3;
        int npf  = fi >> 2;
        int row  = 16 * kt + 8 * (lane >> 5) + j;   // k index = n (contraction)
        int col  = 32 * npf + (lane & 31);          // row of W^T = n'
        wf[f] = (unsigned short)f2bf(W_h[(d << 12) + (row << 6) + col]);
    }
    if (t < 384) {   // bias, pre-scaled into exp2 domain
        int q = t & 15, h2 = (t >> 4) & 1, nf = (t >> 5) & 1, d = t >> 6;
        int n = 32 * nf + 4 * h2 + (q & 3) + 8 * (q >> 2);
        bc_s[t] = C2 * b_h[d * 64 + n];
    }
    if (t < 64) {    // W_in/b_in/W_out in C-frag-row order [nf][hi][q]
        int q = t & 15, h2 = (t >> 4) & 1, nf = (t >> 5) & 1;
        int n = 32 * nf + 4 * h2 + (q & 3) + 8 * (q >> 2);
        win_s[t] = W_in[n]; bin_s[t] = b_in[n]; wout_s[t] = W_out[n];
    }
    // ---- r for this wave's 64 sensors ----
    const float x0 = x[blk * 2 + 0], x1 = x[blk * 2 + 1];
    {
        const float* yr = yu + (b * NS + wv * 64 + l) * 5;
        float d0 = x0 - yr[3], d1 = x1 - yr[4];
        r_s[wv * 64 + l] = d0 * d0 + d1 * d1;
    }
    __syncthreads();

    const float rm0 = r_s[wv * 64 + c];        // sensor col for mf=0
    const float rm1 = r_s[wv * 64 + 32 + c];   // mf=1

    // ---- input layer: T[n][m] = r_m*W_in[n]+b_in[n], C-frag layout ----
    float T[2][2][16];
    #pragma unroll
    for (int nf = 0; nf < 2; ++nf)
        #pragma unroll
        for (int qc = 0; qc < 4; ++qc) {
            f32x4 w4 = *(const f32x4*)(win_s + (nf * 2 + hi) * 16 + qc * 4);
            f32x4 b4 = *(const f32x4*)(bin_s + (nf * 2 + hi) * 16 + qc * 4);
            #pragma unroll
            for (int r = 0; r < 4; ++r) {
                T[nf][0][qc * 4 + r] = fmaf(rm0, w4[r], b4[r]);
                T[nf][1][qc * 4 + r] = fmaf(rm1, w4[r], b4[r]);
            }
        }

    const char*  awf = smem + WF_OFF + l * 16;                   // + d*8192 + frag*1024
    const float* abc = (const float*)(smem + BC_OFF) + hi * 16;  // + d*64 + npf*32 + qc*4

    // ---- 6 residual layers, no barriers ----
    #pragma unroll 1
    for (int d = 0; d < 6; ++d) {
        const char*  awd = awf + d * 8192;
        const float* abd = abc + d * 64;
        #pragma unroll
        for (int mf = 0; mf < 2; ++mf) {
            // pack T[*][mf] (C-layout f32) -> B-frags (bf16, k=hi*8+j)
            unsigned int B[4][4];
            #pragma unroll
            for (int nfs = 0; nfs < 2; ++nfs) {
                unsigned int P[4][2];
                #pragma unroll
                for (int qq = 0; qq < 4; ++qq) {
                    P[qq][0] = cvtpk(T[nfs][mf][4 * qq + 0], T[nfs][mf][4 * qq + 1]);
                    P[qq][1] = cvtpk(T[nfs][mf][4 * qq + 2], T[nfs][mf][4 * qq + 3]);
                }
                // v_permlane32_swap_b32 vdst, vsrc : vdst.hi <-> vsrc.lo
                //   new vdst = [dst.lo | src.lo]  -> B reg pi   (features 8qq..)
                //   new vsrc = [dst.hi | src.hi]  -> B reg 2+pi (features 8qq+4..)
                #pragma unroll
                for (int pi = 0; pi < 2; ++pi) {
                    asm("v_permlane32_swap_b32 %0, %1" : "+v"(P[0][pi]), "+v"(P[1][pi]));
                    B[2 * nfs][pi]     = P[0][pi];
                    B[2 * nfs][2 + pi] = P[1][pi];
                    asm("v_permlane32_swap_b32 %0, %1" : "+v"(P[2][pi]), "+v"(P[3][pi]));
                    B[2 * nfs + 1][pi]     = P[2][pi];
                    B[2 * nfs + 1][2 + pi] = P[3][pi];
                }
            }
            #pragma unroll
            for (int npf = 0; npf < 2; ++npf) {
                f32x16 z;
                #pragma unroll
                for (int q = 0; q < 16; ++q) z[q] = 0.0f;
                #pragma unroll
                for (int kt = 0; kt < 4; ++kt) {
                    bf16x8 a = *(const bf16x8*)(awd + (npf * 4 + kt) * 1024);
                    uintx4 ub;
                    ub[0] = B[kt][0]; ub[1] = B[kt][1]; ub[2] = B[kt][2]; ub[3] = B[kt][3];
                    bf16x8 vb = __builtin_bit_cast(bf16x8, ub);
                    z = __builtin_amdgcn_mfma_f32_32x32x16_bf16(a, vb, z, 0, 0, 0);
                }
                // epilogue: T += tanh(z+b) = fma(-2, rcp(exp2(C2*z+C2*b)+1), T+1)
                #pragma unroll
                for (int qc = 0; qc < 4; ++qc) {
                    f32x4 bb = *(const f32x4*)(abd + npf * 32 + qc * 4);
                    #pragma unroll
                    for (int r = 0; r < 4; ++r) {
                        int q = qc * 4 + r;
                        float arg = fmaf(z[q], C2, bb[r]);
                        float e   = exp2f(arg);
                        float rc  = __builtin_amdgcn_rcpf(e + 1.0f);
                        T[npf][mf][q] = fmaf(-2.0f, rc, T[npf][mf][q] + 1.0f);
                    }
                }
            }
        }
    }

    // ---- k = T . W_out (+b_out), then integral over sensors ----
    float ps0 = 0.0f, ps1 = 0.0f;
    #pragma unroll
    for (int nf = 0; nf < 2; ++nf)
        #pragma unroll
        for (int qc = 0; qc < 4; ++qc) {
            f32x4 w4 = *(const f32x4*)(wout_s + (nf * 2 + hi) * 16 + qc * 4);
            #pragma unroll
            for (int r = 0; r < 4; ++r) {
                ps0 = fmaf(T[nf][0][qc * 4 + r], w4[r], ps0);
                ps1 = fmaf(T[nf][1][qc * 4 + r], w4[r], ps1);
            }
        }
    ps0 += __shfl_xor(ps0, 32);
    ps1 += __shfl_xor(ps1, 32);
    const float kv = (hi ? ps1 : ps0) + b_out[0];
    const int sl = wv * 64 + hi * 32 + c;
    const float* ur = yu + (b * NS + sl) * 5;
    float v0 = kv * ur[0], v1 = kv * ur[1], v2 = kv * ur[2];
    #pragma unroll
    for (int off = 1; off < 64; off <<= 1) {
        v0 += __shfl_xor(v0, off);
        v1 += __shfl_xor(v1, off);
        v2 += __shfl_xor(v2, off);
    }
    if (l == 0) { part[wv * 3 + 0] = v0; part[wv * 3 + 1] = v1; part[wv * 3 + 2] = v2; }
    __syncthreads();
    if (t < 3) {
        float s = 0.0f;
        #pragma unroll
        for (int w = 0; w < 8; ++w) s += part[w * 3 + t];
        out[blk * 3 + t] = s * (1.0f / 512.0f);
    }
}

extern "C" void kernel_launch(void* const* d_in, const int* in_sizes, int n_in,
                              void* d_out, int out_size, void* d_ws, size_t ws_size,
                              hipStream_t stream) {
    const float* yu    = (const float*)d_in[0];
    const float* x     = (const float*)d_in[1];
    const float* W_in  = (const float*)d_in[2];
    const float* b_in  = (const float*)d_in[3];
    const float* W_h   = (const float*)d_in[4];
    const float* b_h   = (const float*)d_in[5];
    const float* W_out = (const float*)d_in[6];
    const float* b_out = (const float*)d_in[7];
    float* out = (float*)d_out;

    (void)hipFuncSetAttribute((const void*)neurop_kernel,
                              hipFuncAttributeMaxDynamicSharedMemorySize, SMEM_BYTES);
    hipLaunchKernelGGL(neurop_kernel, dim3(BATCH * XS), dim3(NS), SMEM_BYTES, stream,
                       yu, x, W_in, b_in, W_h, b_h, W_out, b_out, out);
}

// Round 6
// 310.788 us; speedup vs baseline: 2.5495x; 1.3303x over previous
//
#include <hip/hip_runtime.h>

#define BATCH 4
#define NS    512
#define XS    1024

typedef float  f32x4  __attribute__((ext_vector_type(4)));
typedef float  f32x16 __attribute__((ext_vector_type(16)));
typedef __bf16 bf16x8 __attribute__((ext_vector_type(8)));
typedef unsigned int uintx4 __attribute__((ext_vector_type(4)));

// LDS layout (bytes)
#define WF_OFF   0        // 6*8*64*16 = 49152 : W^T as 32x32x16 A-frags (bf16)
#define BC_OFF   49152    // 6*2*2*16*4 = 1536 : 2*log2e * b_h, [d][nf][hi][q]
#define WIN_OFF  50688    // 64*4 : W_in  [nf][hi][q]
#define BIN_OFF  50944    // 64*4 : b_in
#define WOUT_OFF 51200    // 64*4 : W_out
#define PART_OFF 51456    // 16*3*4
#define SMEM_BYTES 51648

#define C2 2.8853900817779268f   // 2*log2(e)

__device__ __forceinline__ unsigned int f2bf(float f) {   // fp32->bf16 RNE
    unsigned int u = __float_as_uint(f);
    u += 0x7fffu + ((u >> 16) & 1u);
    return u >> 16;
}
__device__ __forceinline__ unsigned int cvtpk(float lo, float hi) {
    unsigned int r;
    asm("v_cvt_pk_bf16_f32 %0, %1, %2" : "=v"(r) : "v"(lo), "v"(hi));
    return r;
}

extern "C" __global__ __launch_bounds__(1024, 4)
void neurop_kernel(const float* __restrict__ yu, const float* __restrict__ x,
                   const float* __restrict__ W_in, const float* __restrict__ b_in,
                   const float* __restrict__ W_h, const float* __restrict__ b_h,
                   const float* __restrict__ W_out, const float* __restrict__ b_out,
                   float* __restrict__ out)
{
    extern __shared__ char smem[];
    unsigned short* wf  = (unsigned short*)(smem + WF_OFF);
    float* bc_s   = (float*)(smem + BC_OFF);
    float* win_s  = (float*)(smem + WIN_OFF);
    float* bin_s  = (float*)(smem + BIN_OFF);
    float* wout_s = (float*)(smem + WOUT_OFF);
    float* part   = (float*)(smem + PART_OFF);

    const int t  = threadIdx.x;
    const int l  = t & 63;
    const int wv = t >> 6;        // wave 0..15 -> sensors wv*32..wv*32+31
    const int hi = l >> 5;        // 32-lane half (row-octet select)
    const int c  = l & 31;        // sensor col within the 32-wide tile
    const int blk = blockIdx.x;   // b*XS + xi
    const int b   = blk >> 10;

    // ---- stage W^T as A-frags: elem f=((d*8+npf*4+kt)*64+lane)*8+j ----
    #pragma unroll 1
    for (int it = 0; it < 24; ++it) {
        int f    = t + it * 1024;
        int j    = f & 7;
        int lane = (f >> 3) & 63;
        int fi   = (f >> 9) & 7;
        int d    = f >> 12;
        int kt   = fi & 3;
        int npf  = fi >> 2;
        int row  = 16 * kt + 8 * (lane >> 5) + j;   // contraction index k = n
        int col  = 32 * npf + (lane & 31);          // output feature n'
        wf[f] = (unsigned short)f2bf(W_h[(d << 12) + (row << 6) + col]);
    }
    if (t < 384) {   // bias, pre-scaled into exp2 domain, C-frag row order
        int q = t & 15, h2 = (t >> 4) & 1, nf = (t >> 5) & 1, d = t >> 6;
        int n = 32 * nf + 4 * h2 + (q & 3) + 8 * (q >> 2);
        bc_s[t] = C2 * b_h[d * 64 + n];
    }
    if (t < 64) {    // W_in/b_in/W_out in C-frag-row order [nf][hi][q]
        int q = t & 15, h2 = (t >> 4) & 1, nf = (t >> 5) & 1;
        int n = 32 * nf + 4 * h2 + (q & 3) + 8 * (q >> 2);
        win_s[t] = W_in[n]; bin_s[t] = b_in[n]; wout_s[t] = W_out[n];
    }
    __syncthreads();

    // ---- r for this lane's sensor (direct, no LDS) ----
    const float x0 = x[blk * 2 + 0], x1 = x[blk * 2 + 1];
    const int   sl = wv * 32 + c;                 // sensor index
    const float* ur = yu + (b * NS + sl) * 5;
    const float d0 = x0 - ur[3], d1 = x1 - ur[4];
    const float rm = d0 * d0 + d1 * d1;

    // ---- input layer: T[n] = r*W_in[n]+b_in[n], C-frag layout ----
    float T[2][16];
    #pragma unroll
    for (int nf = 0; nf < 2; ++nf)
        #pragma unroll
        for (int qc = 0; qc < 4; ++qc) {
            f32x4 w4 = *(const f32x4*)(win_s + (nf * 2 + hi) * 16 + qc * 4);
            f32x4 b4 = *(const f32x4*)(bin_s + (nf * 2 + hi) * 16 + qc * 4);
            #pragma unroll
            for (int r = 0; r < 4; ++r)
                T[nf][qc * 4 + r] = fmaf(rm, w4[r], b4[r]);
        }

    const char*  awf = smem + WF_OFF + l * 16;                   // + d*8192 + frag*1024
    const float* abc = (const float*)(smem + BC_OFF) + hi * 16;  // + d*64 + npf*32 + qc*4

    // ---- 6 residual layers, no barriers ----
    #pragma unroll 1
    for (int d = 0; d < 6; ++d) {
        const char*  awd = awf + d * 8192;
        const float* abd = abc + d * 64;
        // pack T (C-layout f32) -> B-frags (bf16, k=16*kt+8*hi+j)
        unsigned int B[4][4];
        #pragma unroll
        for (int nfs = 0; nfs < 2; ++nfs) {
            unsigned int P[4][2];
            #pragma unroll
            for (int qq = 0; qq < 4; ++qq) {
                P[qq][0] = cvtpk(T[nfs][4 * qq + 0], T[nfs][4 * qq + 1]);
                P[qq][1] = cvtpk(T[nfs][4 * qq + 2], T[nfs][4 * qq + 3]);
            }
            // v_permlane32_swap_b32 vdst, vsrc : new vdst=[dst.lo|src.lo] -> reg pi
            //                                    new vsrc=[dst.hi|src.hi] -> reg 2+pi
            #pragma unroll
            for (int pi = 0; pi < 2; ++pi) {
                asm("v_permlane32_swap_b32 %0, %1" : "+v"(P[0][pi]), "+v"(P[1][pi]));
                B[2 * nfs][pi]     = P[0][pi];
                B[2 * nfs][2 + pi] = P[1][pi];
                asm("v_permlane32_swap_b32 %0, %1" : "+v"(P[2][pi]), "+v"(P[3][pi]));
                B[2 * nfs + 1][pi]     = P[2][pi];
                B[2 * nfs + 1][2 + pi] = P[3][pi];
            }
        }
        #pragma unroll
        for (int npf = 0; npf < 2; ++npf) {
            f32x16 z;
            #pragma unroll
            for (int q = 0; q < 16; ++q) z[q] = 0.0f;
            #pragma unroll
            for (int kt = 0; kt < 4; ++kt) {
                bf16x8 a = *(const bf16x8*)(awd + (npf * 4 + kt) * 1024);
                uintx4 ub;
                ub[0] = B[kt][0]; ub[1] = B[kt][1]; ub[2] = B[kt][2]; ub[3] = B[kt][3];
                bf16x8 vb = __builtin_bit_cast(bf16x8, ub);
                z = __builtin_amdgcn_mfma_f32_32x32x16_bf16(a, vb, z, 0, 0, 0);
            }
            // epilogue: T += tanh(z+b) = fma(-2, rcp(exp2(C2*z+C2*b)+1), T+1)
            #pragma unroll
            for (int qc = 0; qc < 4; ++qc) {
                f32x4 bb = *(const f32x4*)(abd + npf * 32 + qc * 4);
                #pragma unroll
                for (int r = 0; r < 4; ++r) {
                    int q = qc * 4 + r;
                    float arg = fmaf(z[q], C2, bb[r]);
                    float e   = __builtin_amdgcn_exp2f(arg);   // raw v_exp_f32
                    float rc  = __builtin_amdgcn_rcpf(e + 1.0f);
                    T[npf][q] = fmaf(-2.0f, rc, T[npf][q] + 1.0f);
                }
            }
        }
    }

    // ---- k = T . W_out (+b_out), then integral over sensors ----
    float ps = 0.0f;
    #pragma unroll
    for (int nf = 0; nf < 2; ++nf)
        #pragma unroll
        for (int qc = 0; qc < 4; ++qc) {
            f32x4 w4 = *(const f32x4*)(wout_s + (nf * 2 + hi) * 16 + qc * 4);
            #pragma unroll
            for (int r = 0; r < 4; ++r)
                ps = fmaf(T[nf][qc * 4 + r], w4[r], ps);
        }
    ps += __shfl_xor(ps, 32);                  // full 64-feature dot, duplicated in halves
    const float kv = ps + b_out[0];
    float v0 = kv * ur[0], v1 = kv * ur[1], v2 = kv * ur[2];
    #pragma unroll
    for (int off = 1; off < 64; off <<= 1) {   // sums 2x over the 32 sensors
        v0 += __shfl_xor(v0, off);
        v1 += __shfl_xor(v1, off);
        v2 += __shfl_xor(v2, off);
    }
    if (l == 0) { part[wv * 3 + 0] = v0; part[wv * 3 + 1] = v1; part[wv * 3 + 2] = v2; }
    __syncthreads();
    if (t < 3) {
        float s = 0.0f;
        #pragma unroll
        for (int w = 0; w < 16; ++w) s += part[w * 3 + t];
        out[blk * 3 + t] = s * (1.0f / 1024.0f);   // /512 sensors, /2 half-duplication
    }
}

extern "C" void kernel_launch(void* const* d_in, const int* in_sizes, int n_in,
                              void* d_out, int out_size, void* d_ws, size_t ws_size,
                              hipStream_t stream) {
    const float* yu    = (const float*)d_in[0];
    const float* x     = (const float*)d_in[1];
    const float* W_in  = (const float*)d_in[2];
    const float* b_in  = (const float*)d_in[3];
    const float* W_h   = (const float*)d_in[4];
    const float* b_h   = (const float*)d_in[5];
    const float* W_out = (const float*)d_in[6];
    const float* b_out = (const float*)d_in[7];
    float* out = (float*)d_out;

    (void)hipFuncSetAttribute((const void*)neurop_kernel,
                              hipFuncAttributeMaxDynamicSharedMemorySize, SMEM_BYTES);
    hipLaunchKernelGGL(neurop_kernel, dim3(BATCH * XS), dim3(1024), SMEM_BYTES, stream,
                       yu, x, W_in, b_in, W_h, b_h, W_out, b_out, out);
}

// Round 7
// 302.710 us; speedup vs baseline: 2.6175x; 1.0267x over previous
//
#include <hip/hip_runtime.h>

#define BATCH 4
#define NS    512
#define XS    1024

typedef float  f32x2  __attribute__((ext_vector_type(2)));
typedef float  f32x4  __attribute__((ext_vector_type(4)));
typedef float  f32x16 __attribute__((ext_vector_type(16)));
typedef __bf16 bf16x8 __attribute__((ext_vector_type(8)));
typedef unsigned int uintx4 __attribute__((ext_vector_type(4)));

// ws image == LDS image (bytes):
//   [0,49152)      W_h as 32x32x16 A-frags, bf16
//   [49152,50688)  C2*b_h, C-frag row order [d][npf][hi][q], f32 (384)
//   [50688,50944)  W_in  [nf][hi][q]
//   [50944,51200)  b_in
//   [51200,51456)  W_out
// partials in ws at 52224: 8192 blocks * 3 f32
#define IMG_BYTES  51456
#define PART_WS_OFF 52224
#define PART_OFF   51456      // LDS-only: 8 waves * 3 f32
#define SMEM_BYTES 51552

#define C2 2.8853900817779268f   // 2*log2(e)

__device__ __forceinline__ unsigned int f2bf(float f) {   // fp32->bf16 RNE
    unsigned int u = __float_as_uint(f);
    u += 0x7fffu + ((u >> 16) & 1u);
    return u >> 16;
}
__device__ __forceinline__ unsigned int cvtpk(float lo, float hi) {
    unsigned int r;
    asm("v_cvt_pk_bf16_f32 %0, %1, %2" : "=v"(r) : "v"(lo), "v"(hi));
    return r;
}
__device__ __forceinline__ f32x2 pk_fma(f32x2 a, f32x2 b, f32x2 c) {
    f32x2 d;
    asm("v_pk_fma_f32 %0, %1, %2, %3" : "=v"(d) : "v"(a), "v"(b), "v"(c));
    return d;
}
__device__ __forceinline__ f32x2 pk_add(f32x2 a, f32x2 b) {
    f32x2 d;
    asm("v_pk_add_f32 %0, %1, %2" : "=v"(d) : "v"(a), "v"(b));
    return d;
}

// ---- one-time (per launch) image builder: W-frags + permuted params ----
extern "C" __global__ void neurop_setup(const float* __restrict__ W_h,
                                        const float* __restrict__ b_h,
                                        const float* __restrict__ W_in,
                                        const float* __restrict__ b_in,
                                        const float* __restrict__ W_out,
                                        char* __restrict__ ws)
{
    int gid = blockIdx.x * 256 + threadIdx.x;
    if (gid < 24576) {      // W-frag elem f=((d*8+npf*4+kt)*64+lane)*8+j
        int f = gid;
        int j = f & 7, lane = (f >> 3) & 63, fi = (f >> 9) & 7, d = f >> 12;
        int kt = fi & 3, npf = fi >> 2;
        int row = 16 * kt + 8 * (lane >> 5) + j;
        int col = 32 * npf + (lane & 31);
        ((unsigned short*)ws)[f] = (unsigned short)f2bf(W_h[(d << 12) + (row << 6) + col]);
    } else {
        int g2 = gid - 24576;               // 0..767
        if (g2 < 384) {                     // bias, C2-scaled, C-frag order
            int q = g2 & 15, h2 = (g2 >> 4) & 1, nf = (g2 >> 5) & 1, d = g2 >> 6;
            int n = 32 * nf + 4 * h2 + (q & 3) + 8 * (q >> 2);
            ((float*)(ws + 49152))[g2] = C2 * b_h[d * 64 + n];
        } else {
            int e = g2 - 384;               // 0..383, need 0..191
            int which = e >> 6;
            if (which < 3) {
                int q = e & 15, h2 = (e >> 4) & 1, nf = (e >> 5) & 1;
                int n = 32 * nf + 4 * h2 + (q & 3) + 8 * (q >> 2);
                const float* src = which == 0 ? W_in : (which == 1 ? b_in : W_out);
                ((float*)(ws + 50688 + which * 256))[e & 63] = src[n];
            }
        }
    }
}

// ---- main: 512 threads = 8 waves = 256 sensors; 2 blocks per x-point ----
extern "C" __global__ __launch_bounds__(512, 6)
void neurop_kernel(const float* __restrict__ yu, const float* __restrict__ x,
                   const float* __restrict__ b_out,
                   const char* __restrict__ ws, float* __restrict__ part_out)
{
    extern __shared__ char smem[];
    const int t  = threadIdx.x;
    const int l  = t & 63;
    const int wv = t >> 6;        // wave 0..7
    const int hi = l >> 5;
    const int c  = l & 31;
    const int blk  = blockIdx.x;  // xp*2 + half
    const int xp   = blk >> 1;    // b*XS + xi
    const int half = blk & 1;
    const int b    = xp >> 10;

    // ---- stage the 51456-B image: 6x16B + 2x4B global_load_lds ----
    #pragma unroll
    for (int it = 0; it < 6; ++it)
        __builtin_amdgcn_global_load_lds((const int*)(ws + it * 8192 + t * 16),
                                         (int*)(smem + it * 8192 + t * 16), 16, 0, 0);
    __builtin_amdgcn_global_load_lds((const int*)(ws + 49152 + t * 4),
                                     (int*)(smem + 49152 + t * 4), 4, 0, 0);
    if (t < 64)
        __builtin_amdgcn_global_load_lds((const int*)(ws + 51200 + t * 4),
                                         (int*)(smem + 51200 + t * 4), 4, 0, 0);

    const float* win_s  = (const float*)(smem + 50688);
    const float* bin_s  = (const float*)(smem + 50944);
    const float* wout_s = (const float*)(smem + 51200);
    float* part = (float*)(smem + PART_OFF);
    __syncthreads();

    // ---- r for this lane's sensor ----
    const float x0 = x[xp * 2 + 0], x1 = x[xp * 2 + 1];
    const int   sl = half * 256 + wv * 32 + c;
    const float* ur = yu + (b * NS + sl) * 5;
    const float d0 = x0 - ur[3], d1 = x1 - ur[4];
    const float rm = d0 * d0 + d1 * d1;

    // ---- input layer: T[n] = r*W_in[n]+b_in[n], C-frag layout (as pairs) ----
    f32x2 T2[2][8];
    #pragma unroll
    for (int nf = 0; nf < 2; ++nf)
        #pragma unroll
        for (int qc = 0; qc < 4; ++qc) {
            f32x4 w4 = *(const f32x4*)(win_s + (nf * 2 + hi) * 16 + qc * 4);
            f32x4 b4 = *(const f32x4*)(bin_s + (nf * 2 + hi) * 16 + qc * 4);
            T2[nf][qc * 2 + 0] = (f32x2){fmaf(rm, w4[0], b4[0]), fmaf(rm, w4[1], b4[1])};
            T2[nf][qc * 2 + 1] = (f32x2){fmaf(rm, w4[2], b4[2]), fmaf(rm, w4[3], b4[3])};
        }

    const char*  awf = smem + l * 16;                            // + d*8192 + frag*1024
    const float* abc = (const float*)(smem + 49152) + hi * 16;   // + d*64 + npf*32

    const f32x2 c2p  = (f32x2){C2, C2};
    const f32x2 one2 = (f32x2){1.0f, 1.0f};
    const f32x2 m2p  = (f32x2){-2.0f, -2.0f};

    // ---- 6 residual layers ----
    #pragma unroll 1
    for (int d = 0; d < 6; ++d) {
        const char*  awd = awf + d * 8192;
        const float* abd = abc + d * 64;
        // pack T (C-layout f32) -> B-frags (bf16, k=16*kt+8*hi+j)
        unsigned int B[4][4];
        #pragma unroll
        for (int nfs = 0; nfs < 2; ++nfs) {
            unsigned int P[4][2];
            #pragma unroll
            for (int qq = 0; qq < 4; ++qq) {
                P[qq][0] = cvtpk(T2[nfs][2 * qq + 0].x, T2[nfs][2 * qq + 0].y);
                P[qq][1] = cvtpk(T2[nfs][2 * qq + 1].x, T2[nfs][2 * qq + 1].y);
            }
            #pragma unroll
            for (int pi = 0; pi < 2; ++pi) {
                asm("v_permlane32_swap_b32 %0, %1" : "+v"(P[0][pi]), "+v"(P[1][pi]));
                B[2 * nfs][pi]     = P[0][pi];
                B[2 * nfs][2 + pi] = P[1][pi];
                asm("v_permlane32_swap_b32 %0, %1" : "+v"(P[2][pi]), "+v"(P[3][pi]));
                B[2 * nfs + 1][pi]     = P[2][pi];
                B[2 * nfs + 1][2 + pi] = P[3][pi];
            }
        }
        #pragma unroll
        for (int npf = 0; npf < 2; ++npf) {
            f32x16 z;
            #pragma unroll
            for (int q = 0; q < 16; ++q) z[q] = 0.0f;
            #pragma unroll
            for (int kt = 0; kt < 4; ++kt) {
                bf16x8 a = *(const bf16x8*)(awd + (npf * 4 + kt) * 1024);
                uintx4 ub;
                ub[0] = B[kt][0]; ub[1] = B[kt][1]; ub[2] = B[kt][2]; ub[3] = B[kt][3];
                bf16x8 vb = __builtin_bit_cast(bf16x8, ub);
                z = __builtin_amdgcn_mfma_f32_32x32x16_bf16(a, vb, z, 0, 0, 0);
            }
            // epilogue (pairs): T += tanh(z+b) = fma(-2, rcp(exp2(C2*z+C2b)+1), T+1)
            #pragma unroll
            for (int p = 0; p < 8; ++p) {
                f32x2 z2  = (f32x2){z[2 * p], z[2 * p + 1]};
                f32x2 bb2 = *(const f32x2*)(abd + npf * 32 + 2 * p);
                f32x2 arg = pk_fma(z2, c2p, bb2);
                f32x2 e2;
                e2.x = __builtin_amdgcn_exp2f(arg.x);
                e2.y = __builtin_amdgcn_exp2f(arg.y);
                f32x2 ep = pk_add(e2, one2);
                f32x2 rc;
                rc.x = __builtin_amdgcn_rcpf(ep.x);
                rc.y = __builtin_amdgcn_rcpf(ep.y);
                f32x2 T1 = pk_add(T2[npf][p], one2);
                T2[npf][p] = pk_fma(rc, m2p, T1);
            }
        }
    }

    // ---- k = T . W_out (+b_out), then partial integral over 256 sensors ----
    float ps = 0.0f;
    #pragma unroll
    for (int nf = 0; nf < 2; ++nf)
        #pragma unroll
        for (int qc = 0; qc < 4; ++qc) {
            f32x4 w4 = *(const f32x4*)(wout_s + (nf * 2 + hi) * 16 + qc * 4);
            ps = fmaf(T2[nf][qc * 2 + 0].x, w4[0], ps);
            ps = fmaf(T2[nf][qc * 2 + 0].y, w4[1], ps);
            ps = fmaf(T2[nf][qc * 2 + 1].x, w4[2], ps);
            ps = fmaf(T2[nf][qc * 2 + 1].y, w4[3], ps);
        }
    ps += __shfl_xor(ps, 32);                 // full 64-feature dot in both halves
    const float kv = ps + b_out[0];
    float v0 = kv * ur[0], v1 = kv * ur[1], v2 = kv * ur[2];
    #pragma unroll
    for (int off = 1; off < 64; off <<= 1) {  // sums each sensor twice (hi halves)
        v0 += __shfl_xor(v0, off);
        v1 += __shfl_xor(v1, off);
        v2 += __shfl_xor(v2, off);
    }
    if (l == 0) { part[wv * 3 + 0] = v0; part[wv * 3 + 1] = v1; part[wv * 3 + 2] = v2; }
    __syncthreads();
    if (t < 3) {
        float s = 0.0f;
        #pragma unroll
        for (int w = 0; w < 8; ++w) s += part[w * 3 + t];
        part_out[blk * 3 + t] = s;
    }
}

// ---- combine the two sensor-halves of each x-point ----
extern "C" __global__ void neurop_reduce(const float* __restrict__ part, float* __restrict__ out)
{
    int i = blockIdx.x * 256 + threadIdx.x;
    if (i >= BATCH * XS * 3) return;
    int xp = i / 3, ch = i - 3 * xp;
    out[i] = (part[6 * xp + ch] + part[6 * xp + ch + 3]) * (1.0f / 1024.0f);
}

extern "C" void kernel_launch(void* const* d_in, const int* in_sizes, int n_in,
                              void* d_out, int out_size, void* d_ws, size_t ws_size,
                              hipStream_t stream) {
    const float* yu    = (const float*)d_in[0];
    const float* x     = (const float*)d_in[1];
    const float* W_in  = (const float*)d_in[2];
    const float* b_in  = (const float*)d_in[3];
    const float* W_h   = (const float*)d_in[4];
    const float* b_h   = (const float*)d_in[5];
    const float* W_out = (const float*)d_in[6];
    const float* b_out = (const float*)d_in[7];
    float* out = (float*)d_out;
    char* ws = (char*)d_ws;
    float* part = (float*)(ws + PART_WS_OFF);

    hipLaunchKernelGGL(neurop_setup, dim3(99), dim3(256), 0, stream,
                       W_h, b_h, W_in, b_in, W_out, ws);

    (void)hipFuncSetAttribute((const void*)neurop_kernel,
                              hipFuncAttributeMaxDynamicSharedMemorySize, SMEM_BYTES);
    hipLaunchKernelGGL(neurop_kernel, dim3(BATCH * XS * 2), dim3(512), SMEM_BYTES, stream,
                       yu, x, b_out, (const char*)ws, part);

    hipLaunchKernelGGL(neurop_reduce, dim3(48), dim3(256), 0, stream,
                       (const float*)part, out);
}

// Round 8
// 236.494 us; speedup vs baseline: 3.3504x; 1.2800x over previous
//
#include <hip/hip_runtime.h>

#define BATCH 4
#define NS    512
#define XS    1024

typedef float  f32x4  __attribute__((ext_vector_type(4)));
typedef float  f32x16 __attribute__((ext_vector_type(16)));
typedef __bf16 bf16x8 __attribute__((ext_vector_type(8)));
typedef unsigned int uintx4 __attribute__((ext_vector_type(4)));

// ws image == LDS image (bytes):
//   [0,49152)      W_h as 32x32x16 A-frags, bf16
//   [49152,50688)  C2*b_h, C-frag row order [d][npf][hi][q], f32 (384)
//   [50688,50944)  W_in  [nf][hi][q]
//   [50944,51200)  b_in
//   [51200,51456)  W_out
// partials in ws at 52224: 8192 blocks * 3 f32
#define IMG_BYTES  51456
#define PART_WS_OFF 52224
#define PART_OFF   51456      // LDS-only: 8 waves * 3 f32
#define SMEM_BYTES 51552

#define C2 2.8853900817779268f   // 2*log2(e)

__device__ __forceinline__ unsigned int f2bf(float f) {   // fp32->bf16 RNE
    unsigned int u = __float_as_uint(f);
    u += 0x7fffu + ((u >> 16) & 1u);
    return u >> 16;
}
__device__ __forceinline__ unsigned int cvtpk(float lo, float hi) {
    unsigned int r;
    asm("v_cvt_pk_bf16_f32 %0, %1, %2" : "=v"(r) : "v"(lo), "v"(hi));
    return r;
}

// ---- one-time (per launch) image builder: W-frags + permuted params ----
extern "C" __global__ void neurop_setup(const float* __restrict__ W_h,
                                        const float* __restrict__ b_h,
                                        const float* __restrict__ W_in,
                                        const float* __restrict__ b_in,
                                        const float* __restrict__ W_out,
                                        char* __restrict__ ws)
{
    int gid = blockIdx.x * 256 + threadIdx.x;
    if (gid < 24576) {      // W-frag elem f=((d*8+npf*4+kt)*64+lane)*8+j
        int f = gid;
        int j = f & 7, lane = (f >> 3) & 63, fi = (f >> 9) & 7, d = f >> 12;
        int kt = fi & 3, npf = fi >> 2;
        int row = 16 * kt + 8 * (lane >> 5) + j;
        int col = 32 * npf + (lane & 31);
        ((unsigned short*)ws)[f] = (unsigned short)f2bf(W_h[(d << 12) + (row << 6) + col]);
    } else {
        int g2 = gid - 24576;               // 0..767
        if (g2 < 384) {                     // bias, C2-scaled, C-frag order
            int q = g2 & 15, h2 = (g2 >> 4) & 1, nf = (g2 >> 5) & 1, d = g2 >> 6;
            int n = 32 * nf + 4 * h2 + (q & 3) + 8 * (q >> 2);
            ((float*)(ws + 49152))[g2] = C2 * b_h[d * 64 + n];
        } else {
            int e = g2 - 384;               // 0..383, need 0..191
            int which = e >> 6;
            if (which < 3) {
                int q = e & 15, h2 = (e >> 4) & 1, nf = (e >> 5) & 1;
                int n = 32 * nf + 4 * h2 + (q & 3) + 8 * (q >> 2);
                const float* src = which == 0 ? W_in : (which == 1 ? b_in : W_out);
                ((float*)(ws + 50688 + which * 256))[e & 63] = src[n];
            }
        }
    }
}

// ---- main: 512 threads = 8 waves = 256 sensors; 2 blocks per x-point ----
extern "C" __global__ __launch_bounds__(512, 6)
void neurop_kernel(const float* __restrict__ yu, const float* __restrict__ x,
                   const float* __restrict__ b_out,
                   const char* __restrict__ ws, float* __restrict__ part_out)
{
    extern __shared__ char smem[];
    const int t  = threadIdx.x;
    const int l  = t & 63;
    const int wv = t >> 6;        // wave 0..7
    const int hi = l >> 5;
    const int c  = l & 31;
    const int blk  = blockIdx.x;  // xp*2 + half
    const int xp   = blk >> 1;    // b*XS + xi
    const int half = blk & 1;
    const int b    = xp >> 10;

    // ---- stage the 51456-B image: 6x16B + 2x4B global_load_lds ----
    #pragma unroll
    for (int it = 0; it < 6; ++it)
        __builtin_amdgcn_global_load_lds((const int*)(ws + it * 8192 + t * 16),
                                         (int*)(smem + it * 8192 + t * 16), 16, 0, 0);
    __builtin_amdgcn_global_load_lds((const int*)(ws + 49152 + t * 4),
                                     (int*)(smem + 49152 + t * 4), 4, 0, 0);
    if (t < 64)
        __builtin_amdgcn_global_load_lds((const int*)(ws + 51200 + t * 4),
                                         (int*)(smem + 51200 + t * 4), 4, 0, 0);

    const float* win_s  = (const float*)(smem + 50688);
    const float* bin_s  = (const float*)(smem + 50944);
    const float* wout_s = (const float*)(smem + 51200);
    float* part = (float*)(smem + PART_OFF);
    __syncthreads();

    // ---- r for this lane's sensor ----
    const float x0 = x[xp * 2 + 0], x1 = x[xp * 2 + 1];
    const int   sl = half * 256 + wv * 32 + c;
    const float* ur = yu + (b * NS + sl) * 5;
    const float d0 = x0 - ur[3], d1 = x1 - ur[4];
    const float rm = d0 * d0 + d1 * d1;

    // ---- input layer: T[n] = r*W_in[n]+b_in[n], C-frag layout ----
    float T[2][16];
    #pragma unroll
    for (int nf = 0; nf < 2; ++nf)
        #pragma unroll
        for (int qc = 0; qc < 4; ++qc) {
            f32x4 w4 = *(const f32x4*)(win_s + (nf * 2 + hi) * 16 + qc * 4);
            f32x4 b4 = *(const f32x4*)(bin_s + (nf * 2 + hi) * 16 + qc * 4);
            #pragma unroll
            for (int r = 0; r < 4; ++r)
                T[nf][qc * 4 + r] = fmaf(rm, w4[r], b4[r]);
        }

    const char*  awf = smem + l * 16;                            // + d*8192 + frag*1024
    const float* abc = (const float*)(smem + 49152) + hi * 16;   // + d*64 + npf*32

    // ---- 6 residual layers ----
    #pragma unroll 1
    for (int d = 0; d < 6; ++d) {
        const char*  awd = awf + d * 8192;
        const float* abd = abc + d * 64;
        // pack T (C-layout f32) -> B-frags (bf16, k=16*kt+8*hi+j)
        unsigned int B[4][4];
        #pragma unroll
        for (int nfs = 0; nfs < 2; ++nfs) {
            unsigned int P[4][2];
            #pragma unroll
            for (int qq = 0; qq < 4; ++qq) {
                P[qq][0] = cvtpk(T[nfs][4 * qq + 0], T[nfs][4 * qq + 1]);
                P[qq][1] = cvtpk(T[nfs][4 * qq + 2], T[nfs][4 * qq + 3]);
            }
            // v_permlane32_swap_b32 vdst, vsrc : new vdst=[dst.lo|src.lo] -> reg pi
            //                                    new vsrc=[dst.hi|src.hi] -> reg 2+pi
            #pragma unroll
            for (int pi = 0; pi < 2; ++pi) {
                asm("v_permlane32_swap_b32 %0, %1" : "+v"(P[0][pi]), "+v"(P[1][pi]));
                B[2 * nfs][pi]     = P[0][pi];
                B[2 * nfs][2 + pi] = P[1][pi];
                asm("v_permlane32_swap_b32 %0, %1" : "+v"(P[2][pi]), "+v"(P[3][pi]));
                B[2 * nfs + 1][pi]     = P[2][pi];
                B[2 * nfs + 1][2 + pi] = P[3][pi];
            }
        }
        #pragma unroll
        for (int npf = 0; npf < 2; ++npf) {
            f32x16 z;
            #pragma unroll
            for (int q = 0; q < 16; ++q) z[q] = 0.0f;
            #pragma unroll
            for (int kt = 0; kt < 4; ++kt) {
                bf16x8 a = *(const bf16x8*)(awd + (npf * 4 + kt) * 1024);
                uintx4 ub;
                ub[0] = B[kt][0]; ub[1] = B[kt][1]; ub[2] = B[kt][2]; ub[3] = B[kt][3];
                bf16x8 vb = __builtin_bit_cast(bf16x8, ub);
                z = __builtin_amdgcn_mfma_f32_32x32x16_bf16(a, vb, z, 0, 0, 0);
            }
            // epilogue: T += tanh(z+b) = fma(-2, rcp(exp2(C2*z+C2b)+1), T+1)
            #pragma unroll
            for (int qc = 0; qc < 4; ++qc) {
                f32x4 bb = *(const f32x4*)(abd + npf * 32 + qc * 4);
                #pragma unroll
                for (int r = 0; r < 4; ++r) {
                    int q = qc * 4 + r;
                    float arg = fmaf(z[q], C2, bb[r]);
                    float e   = __builtin_amdgcn_exp2f(arg);
                    float rc  = __builtin_amdgcn_rcpf(e + 1.0f);
                    T[npf][q] = fmaf(-2.0f, rc, T[npf][q] + 1.0f);
                }
            }
        }
    }

    // ---- k = T . W_out (+b_out), then partial integral over 256 sensors ----
    float ps = 0.0f;
    #pragma unroll
    for (int nf = 0; nf < 2; ++nf)
        #pragma unroll
        for (int qc = 0; qc < 4; ++qc) {
            f32x4 w4 = *(const f32x4*)(wout_s + (nf * 2 + hi) * 16 + qc * 4);
            #pragma unroll
            for (int r = 0; r < 4; ++r)
                ps = fmaf(T[nf][qc * 4 + r], w4[r], ps);
        }
    ps += __shfl_xor(ps, 32);                 // full 64-feature dot in both halves
    const float kv = ps + b_out[0];
    float v0 = kv * ur[0], v1 = kv * ur[1], v2 = kv * ur[2];
    #pragma unroll
    for (int off = 1; off < 64; off <<= 1) {  // sums each sensor twice (hi halves)
        v0 += __shfl_xor(v0, off);
        v1 += __shfl_xor(v1, off);
        v2 += __shfl_xor(v2, off);
    }
    if (l == 0) { part[wv * 3 + 0] = v0; part[wv * 3 + 1] = v1; part[wv * 3 + 2] = v2; }
    __syncthreads();
    if (t < 3) {
        float s = 0.0f;
        #pragma unroll
        for (int w = 0; w < 8; ++w) s += part[w * 3 + t];
        part_out[blk * 3 + t] = s;
    }
}

// ---- combine the two sensor-halves of each x-point ----
extern "C" __global__ void neurop_reduce(const float* __restrict__ part, float* __restrict__ out)
{
    int i = blockIdx.x * 256 + threadIdx.x;
    if (i >= BATCH * XS * 3) return;
    int xp = i / 3, ch = i - 3 * xp;
    out[i] = (part[6 * xp + ch] + part[6 * xp + ch + 3]) * (1.0f / 1024.0f);
}

extern "C" void kernel_launch(void* const* d_in, const int* in_sizes, int n_in,
                              void* d_out, int out_size, void* d_ws, size_t ws_size,
                              hipStream_t stream) {
    const float* yu    = (const float*)d_in[0];
    const float* x     = (const float*)d_in[1];
    const float* W_in  = (const float*)d_in[2];
    const float* b_in  = (const float*)d_in[3];
    const float* W_h   = (const float*)d_in[4];
    const float* b_h   = (const float*)d_in[5];
    const float* W_out = (const float*)d_in[6];
    const float* b_out = (const float*)d_in[7];
    float* out = (float*)d_out;
    char* ws = (char*)d_ws;
    float* part = (float*)(ws + PART_WS_OFF);

    hipLaunchKernelGGL(neurop_setup, dim3(99), dim3(256), 0, stream,
                       W_h, b_h, W_in, b_in, W_out, ws);

    (void)hipFuncSetAttribute((const void*)neurop_kernel,
                              hipFuncAttributeMaxDynamicSharedMemorySize, SMEM_BYTES);
    hipLaunchKernelGGL(neurop_kernel, dim3(BATCH * XS * 2), dim3(512), SMEM_BYTES, stream,
                       yu, x, b_out, (const char*)ws, part);

    hipLaunchKernelGGL(neurop_reduce, dim3(48), dim3(256), 0, stream,
                       (const float*)part, out);
}

// Round 9
// 182.513 us; speedup vs baseline: 4.3413x; 1.2958x over previous
//
#include <hip/hip_runtime.h>

#define BATCH 4
#define NS    512
#define XS    1024

#define NT    8192
#define RMAX  96.0f
#define HSTEP (RMAX / (float)NT)
#define INVH  ((float)NT / RMAX)

#define C2 2.8853900817779268f   // 2*log2(e)

// ---- Kernel 1: tabulate k(r) at NT points, pure fp32 (thread per entry) ----
extern "C" __global__ void build_k_table(const float* __restrict__ W_in,
                                         const float* __restrict__ b_in,
                                         const float* __restrict__ W_h,
                                         const float* __restrict__ b_h,
                                         const float* __restrict__ W_out,
                                         const float* __restrict__ b_out,
                                         float* __restrict__ K)
{
    const int i = blockIdx.x * 256 + threadIdx.x;
    if (i >= NT) return;
    const float r = (float)i * HSTEP;

    float h[64];
    #pragma unroll
    for (int j = 0; j < 64; ++j)
        h[j] = fmaf(r, W_in[j], b_in[j]);

    #pragma unroll 1
    for (int d = 0; d < 6; ++d) {
        const float* __restrict__ W  = W_h + (d << 12);
        const float* __restrict__ bb = b_h + (d << 6);
        float hn[64];
        #pragma unroll
        for (int j = 0; j < 64; ++j) hn[j] = bb[j];
        #pragma unroll
        for (int i2 = 0; i2 < 64; ++i2) {
            const float hi = h[i2];
            #pragma unroll
            for (int j = 0; j < 64; ++j)
                hn[j] = fmaf(hi, W[(i2 << 6) + j], hn[j]);
        }
        // h += tanh(hn):  tanh(z) = 1 - 2/(exp2(C2*z)+1)   (v_exp + v_rcp, ~1e-7 abs err)
        #pragma unroll
        for (int j = 0; j < 64; ++j) {
            float e  = __builtin_amdgcn_exp2f(C2 * hn[j]);
            float rc = __builtin_amdgcn_rcpf(e + 1.0f);
            h[j] = fmaf(-2.0f, rc, h[j] + 1.0f);
        }
    }

    float k = b_out[0];
    #pragma unroll
    for (int j = 0; j < 64; ++j)
        k = fmaf(h[j], W_out[j], k);
    K[i] = k;
}

// ---- Kernel 2: per x-point, interp k(r) per sensor, reduce k*u over sensors ----
extern "C" __global__ __launch_bounds__(512)
void integrate(const float* __restrict__ yu, const float* __restrict__ x,
               const float* __restrict__ K, float* __restrict__ out)
{
    __shared__ float part[8][3];
    const int xp = blockIdx.x;        // b*XS + xi
    const int b  = xp >> 10;
    const int s  = threadIdx.x;       // sensor
    const int wv = s >> 6, l = s & 63;

    const float x0 = x[xp * 2 + 0];
    const float x1 = x[xp * 2 + 1];
    const float* ur = yu + (b * NS + s) * 5;
    const float u0 = ur[0], u1 = ur[1], u2 = ur[2];
    const float d0 = x0 - ur[3], d1 = x1 - ur[4];
    const float r  = d0 * d0 + d1 * d1;

    float t = fminf(r * INVH, (float)(NT - 1) - 0.5f);  // guarantees i <= NT-2
    int   i = (int)t;
    float f = t - (float)i;
    float k0 = K[i], k1 = K[i + 1];
    float k  = fmaf(f, k1 - k0, k0);

    float v0 = k * u0, v1 = k * u1, v2 = k * u2;
    #pragma unroll
    for (int off = 32; off > 0; off >>= 1) {
        v0 += __shfl_down(v0, off);
        v1 += __shfl_down(v1, off);
        v2 += __shfl_down(v2, off);
    }
    if (l == 0) { part[wv][0] = v0; part[wv][1] = v1; part[wv][2] = v2; }
    __syncthreads();
    if (s < 3) {
        float acc = 0.0f;
        #pragma unroll
        for (int w = 0; w < 8; ++w) acc += part[w][s];
        out[xp * 3 + s] = acc * (1.0f / (float)NS);
    }
}

extern "C" void kernel_launch(void* const* d_in, const int* in_sizes, int n_in,
                              void* d_out, int out_size, void* d_ws, size_t ws_size,
                              hipStream_t stream) {
    const float* yu    = (const float*)d_in[0];
    const float* x     = (const float*)d_in[1];
    const float* W_in  = (const float*)d_in[2];
    const float* b_in  = (const float*)d_in[3];
    const float* W_h   = (const float*)d_in[4];
    const float* b_h   = (const float*)d_in[5];
    const float* W_out = (const float*)d_in[6];
    const float* b_out = (const float*)d_in[7];
    float* out = (float*)d_out;
    float* K   = (float*)d_ws;    // NT * 4 = 32 KB

    hipLaunchKernelGGL(build_k_table, dim3(NT / 256), dim3(256), 0, stream,
                       W_in, b_in, W_h, b_h, W_out, b_out, K);
    hipLaunchKernelGGL(integrate, dim3(BATCH * XS), dim3(512), 0, stream,
                       yu, x, (const float*)K, out);
}

// Round 10
// 38.649 us; speedup vs baseline: 20.5010x; 4.7223x over previous
//
#include <hip/hip_runtime.h>

#define BATCH 4
#define NS    512
#define XS    1024

#define NT    8192
#define RMAX  96.0f
#define HSTEP (RMAX / (float)NT)
#define INVH  ((float)NT / RMAX)

#define C2 2.8853900817779268f   // 2*log2(e)

__device__ __forceinline__ float bcast(float v, int lane) {   // wave-uniform lane
    return __builtin_bit_cast(float, __builtin_amdgcn_readlane(__builtin_bit_cast(int, v), lane));
}

// ---- Kernel 1: tabulate k(r); one WAVE per entry, one LANE per feature ----
extern "C" __global__ __launch_bounds__(512)
void build_k_table(const float* __restrict__ W_in,
                   const float* __restrict__ b_in,
                   const float* __restrict__ W_h,
                   const float* __restrict__ b_h,
                   const float* __restrict__ W_out,
                   const float* __restrict__ b_out,
                   float* __restrict__ K)
{
    const int wv = threadIdx.x >> 6;            // wave in block
    const int j  = threadIdx.x & 63;            // feature owned by this lane
    const int e  = blockIdx.x * 8 + wv;         // table entry
    const float r = (float)e * HSTEP;

    float h = fmaf(r, W_in[j], b_in[j]);        // h[j] of the input layer

    #pragma unroll 1
    for (int d = 0; d < 6; ++d) {
        const float* __restrict__ W  = W_h + (d << 12);   // W[i][j] row-major
        float hn = b_h[(d << 6) + j];
        #pragma unroll
        for (int i = 0; i < 64; ++i) {
            float hi = bcast(h, i);                        // h[i] broadcast (SGPR)
            hn = fmaf(hi, W[(i << 6) + j], hn);            // lane-coalesced column load
        }
        // h += tanh(hn):  tanh(z) = 1 - 2/(exp2(C2*z)+1)
        float ex = __builtin_amdgcn_exp2f(C2 * hn);
        float rc = __builtin_amdgcn_rcpf(ex + 1.0f);
        h = fmaf(-2.0f, rc, h + 1.0f);
    }

    // k(e) = sum_j h[j]*W_out[j] + b_out  (wave reduction)
    float p = h * W_out[j];
    #pragma unroll
    for (int off = 1; off < 64; off <<= 1)
        p += __shfl_xor(p, off);
    if (j == 0) K[e] = p + b_out[0];
}

// ---- Kernel 2: per x-point, interp k(r) per sensor, reduce k*u over sensors ----
extern "C" __global__ __launch_bounds__(512)
void integrate(const float* __restrict__ yu, const float* __restrict__ x,
               const float* __restrict__ K, float* __restrict__ out)
{
    __shared__ float part[8][3];
    const int xp = blockIdx.x;        // b*XS + xi
    const int b  = xp >> 10;
    const int s  = threadIdx.x;       // sensor
    const int wv = s >> 6, l = s & 63;

    const float x0 = x[xp * 2 + 0];
    const float x1 = x[xp * 2 + 1];
    const float* ur = yu + (b * NS + s) * 5;
    const float u0 = ur[0], u1 = ur[1], u2 = ur[2];
    const float d0 = x0 - ur[3], d1 = x1 - ur[4];
    const float r  = d0 * d0 + d1 * d1;

    float t = fminf(r * INVH, (float)(NT - 1) - 0.5f);  // guarantees i <= NT-2
    int   i = (int)t;
    float f = t - (float)i;
    float k0 = K[i], k1 = K[i + 1];
    float k  = fmaf(f, k1 - k0, k0);

    float v0 = k * u0, v1 = k * u1, v2 = k * u2;
    #pragma unroll
    for (int off = 32; off > 0; off >>= 1) {
        v0 += __shfl_down(v0, off);
        v1 += __shfl_down(v1, off);
        v2 += __shfl_down(v2, off);
    }
    if (l == 0) { part[wv][0] = v0; part[wv][1] = v1; part[wv][2] = v2; }
    __syncthreads();
    if (s < 3) {
        float acc = 0.0f;
        #pragma unroll
        for (int w = 0; w < 8; ++w) acc += part[w][s];
        out[xp * 3 + s] = acc * (1.0f / (float)NS);
    }
}

extern "C" void kernel_launch(void* const* d_in, const int* in_sizes, int n_in,
                              void* d_out, int out_size, void* d_ws, size_t ws_size,
                              hipStream_t stream) {
    const float* yu    = (const float*)d_in[0];
    const float* x     = (const float*)d_in[1];
    const float* W_in  = (const float*)d_in[2];
    const float* b_in  = (const float*)d_in[3];
    const float* W_h   = (const float*)d_in[4];
    const float* b_h   = (const float*)d_in[5];
    const float* W_out = (const float*)d_in[6];
    const float* b_out = (const float*)d_in[7];
    float* out = (float*)d_out;
    float* K   = (float*)d_ws;    // NT * 4 = 32 KB

    hipLaunchKernelGGL(build_k_table, dim3(NT / 8), dim3(512), 0, stream,
                       W_in, b_in, W_h, b_h, W_out, b_out, K);
    hipLaunchKernelGGL(integrate, dim3(BATCH * XS), dim3(512), 0, stream,
                       yu, x, (const float*)K, out);
}